// Round 9
// baseline (457.036 us; speedup 1.0000x reference)
//
#include <hip/hip_runtime.h>
#include <hip/hip_bf16.h>

typedef __bf16 bf16_t;
typedef __bf16 bf16x2 __attribute__((ext_vector_type(2)));
typedef __bf16 bf16x8 __attribute__((ext_vector_type(8)));
typedef float floatx4 __attribute__((ext_vector_type(4)));

#define NTOK 73728   // 8*96*96
#define LNS 136      // padded LDS row stride

// async global->LDS, 16B per lane. LDS dest must be wave-uniform base + lane*16.
__device__ __forceinline__ void gl16(const bf16_t* g, bf16_t* l) {
    __builtin_amdgcn_global_load_lds((const __attribute__((address_space(1))) void*)g,
                                     (__attribute__((address_space(3))) void*)l, 16, 0, 0);
}

// LayerNorm a 64x128 fp32 tile -> bf16 LDS row-major [64][LNS].
__device__ __forceinline__ void stage_ln(const float* __restrict__ src, const float* __restrict__ g,
                                         const float* __restrict__ bta, bf16_t* lnA, int tid) {
    int r = tid >> 2, q = tid & 3;
    const float* rowp = src + (size_t)r * 128 + q * 32;
    float4 v[8];
    float s = 0.0f, sq = 0.0f;
    #pragma unroll
    for (int i = 0; i < 8; i++) {
        v[i] = *(const float4*)(rowp + i * 4);
        s += v[i].x + v[i].y + v[i].z + v[i].w;
        sq += v[i].x * v[i].x + v[i].y * v[i].y + v[i].z * v[i].z + v[i].w * v[i].w;
    }
    s += __shfl_xor(s, 1, 64); sq += __shfl_xor(sq, 1, 64);
    s += __shfl_xor(s, 2, 64); sq += __shfl_xor(sq, 2, 64);
    float m = s * (1.0f / 128.0f);
    float inv = rsqrtf(sq * (1.0f / 128.0f) - m * m + 1e-5f);
    bf16_t* dst = lnA + r * LNS + q * 32;
    #pragma unroll
    for (int i = 0; i < 4; i++) {
        float4 a = v[2 * i], b = v[2 * i + 1];
        float4 g0 = *(const float4*)(g + q * 32 + i * 8);
        float4 g1 = *(const float4*)(g + q * 32 + i * 8 + 4);
        float4 b0 = *(const float4*)(bta + q * 32 + i * 8);
        float4 b1 = *(const float4*)(bta + q * 32 + i * 8 + 4);
        bf16x8 o;
        o[0] = (bf16_t)((a.x - m) * inv * g0.x + b0.x);
        o[1] = (bf16_t)((a.y - m) * inv * g0.y + b0.y);
        o[2] = (bf16_t)((a.z - m) * inv * g0.z + b0.z);
        o[3] = (bf16_t)((a.w - m) * inv * g0.w + b0.w);
        o[4] = (bf16_t)((b.x - m) * inv * g1.x + b1.x);
        o[5] = (bf16_t)((b.y - m) * inv * g1.y + b1.y);
        o[6] = (bf16_t)((b.z - m) * inv * g1.z + b1.z);
        o[7] = (bf16_t)((b.w - m) * inv * g1.w + b1.w);
        *(bf16x8*)(dst + i * 8) = o;
    }
}

// ---------------- weight conversion: fp32 row-major (K,N) -> bf16 MFMA-B-fragment order.
struct TPack {
    const float* src[9];
    bf16_t* dst[9];
    int K[9], N[9];
};
__global__ __launch_bounds__(256) void kconv_frag(TPack p) {
    int seg = blockIdx.y;
    int K = p.K[seg], N = p.N[seg];
    int idx = blockIdx.x * 256 + threadIdx.x;
    if (idx >= K * N) return;
    int j = idx & 7;
    int lane = (idx >> 3) & 63;
    int blk = idx >> 9;
    int tilesK = K >> 5;
    int ntile = blk / tilesK, kc = blk - ntile * tilesK;
    int n = ntile * 16 + (lane & 15);
    int k = kc * 32 + (lane >> 4) * 8 + j;
    p.dst[seg][idx] = (bf16_t)p.src[seg][(size_t)k * N + n];
}

// ---------------- fused LN + qkv GEMM (unchanged from R8)
__global__ __launch_bounds__(256, 4) void kqkv(const float* __restrict__ X,
                                               const float* __restrict__ g, const float* __restrict__ bta,
                                               const bf16_t* __restrict__ Wf,  // frag (384,128) tilesK=4
                                               const float* __restrict__ bias,
                                               bf16_t* __restrict__ out) {
    alignas(16) __shared__ bf16_t lA[64 * LNS];
    const int tid = threadIdx.x;
    const int rowA = blockIdx.y * 64;
    const int rowB = blockIdx.x * 128;
    stage_ln(X + (size_t)rowA * 128, g, bta, lA, tid);
    __syncthreads();
    const int lane = tid & 63, wv = tid >> 6;
    const int frow = lane & 15, fq = lane >> 4;
    const bf16_t* pw = Wf + (size_t)((rowB >> 4) + wv * 2) * 4 * 512 + lane * 8;
    floatx4 acc[4][2] = {};
    #pragma unroll
    for (int kc = 0; kc < 4; kc++) {
        bf16x8 af[4], bfr[2];
        #pragma unroll
        for (int j = 0; j < 2; j++)
            bfr[j] = *(const bf16x8*)(pw + (size_t)(j * 4 + kc) * 512);
        #pragma unroll
        for (int i = 0; i < 4; i++)
            af[i] = *(const bf16x8*)&lA[(i * 16 + frow) * LNS + kc * 32 + fq * 8];
        #pragma unroll
        for (int i = 0; i < 4; i++)
            #pragma unroll
            for (int j = 0; j < 2; j++)
                acc[i][j] = __builtin_amdgcn_mfma_f32_16x16x32_bf16(af[i], bfr[j], acc[i][j], 0, 0, 0);
    }
    #pragma unroll
    for (int j = 0; j < 2; j++) {
        int col = rowB + wv * 32 + j * 16 + frow;
        float bs = bias[col];
        #pragma unroll
        for (int i = 0; i < 4; i++)
            #pragma unroll
            for (int r = 0; r < 4; r++) {
                int row = rowA + i * 16 + fq * 4 + r;
                out[(size_t)row * 384 + col] = (bf16_t)(acc[i][j][r] + bs);
            }
    }
}

// ---------------- fused proj + LN2 + MLP:
//   res2 = res + attn@Wp^T + bp;  out(res buffer) = res2 + gelu(LN(res2)@W1^T+b1)@W2^T + b2
// Block = 64 rows. Wave = 4m x 2n. Zero extra kernel boundary; res2 re-read is L2/L1-hot.
__global__ __launch_bounds__(256, 4) void kfused(const bf16_t* __restrict__ attn,
                                                 const bf16_t* __restrict__ Wpf,  // proj frag (128,128) tilesK=4
                                                 const float* __restrict__ bp,
                                                 const float* __restrict__ resin, // residual base (read)
                                                 float* __restrict__ resout,      // res2 + final (write)
                                                 const float* __restrict__ g, const float* __restrict__ bta,
                                                 const bf16_t* __restrict__ W1f,  // frag (512,128) tilesK=4
                                                 const float* __restrict__ b1,
                                                 const bf16_t* __restrict__ W2f,  // frag (128,512) tilesK=16
                                                 const float* __restrict__ b2) {
    alignas(16) __shared__ bf16_t lA[64 * LNS];   // 17.4 KB: attn panels (16KB) then ln(res2)
    alignas(16) __shared__ bf16_t lH[64 * LNS];   // 17.4 KB h chunk
    __shared__ float psum[4 * 64], psq[4 * 64];   // 2 KB per-wave LN partials
    const int tid = threadIdx.x;
    const int rowA = blockIdx.x * 64;
    const int lane = tid & 63, wv = tid >> 6;
    const int frow = lane & 15, fq = lane >> 4;

    // ---- phase A: stage attn tile into 4 k-panels (alias lA)
    {
        const int sr = tid >> 2, sc = (tid & 3) * 8;
        const bf16_t* pa = attn + (size_t)(rowA + sr) * 128 + sc;
        gl16(pa,      &lA[tid * 8]);
        gl16(pa + 32, &lA[2048 + tid * 8]);
        gl16(pa + 64, &lA[4096 + tid * 8]);
        gl16(pa + 96, &lA[6144 + tid * 8]);
    }
    __syncthreads();

    // ---- phase B: proj gemm
    floatx4 accP[4][2] = {};
    {
        const bf16_t* pw = Wpf + (size_t)(wv * 2) * 4 * 512 + lane * 8;
        #pragma unroll
        for (int kc = 0; kc < 4; kc++) {
            bf16x8 af[4], bfr[2];
            #pragma unroll
            for (int j = 0; j < 2; j++)
                bfr[j] = *(const bf16x8*)(pw + (size_t)(j * 4 + kc) * 512);
            #pragma unroll
            for (int i = 0; i < 4; i++)
                af[i] = *(const bf16x8*)&lA[kc * 2048 + (i * 16 + frow) * 32 + fq * 8];
            #pragma unroll
            for (int i = 0; i < 4; i++)
                #pragma unroll
                for (int j = 0; j < 2; j++)
                    accP[i][j] = __builtin_amdgcn_mfma_f32_16x16x32_bf16(af[i], bfr[j], accP[i][j], 0, 0, 0);
        }
    }

    // ---- phase C: res2 = resin + accP + bp; write; per-row partial LN stats
    {
        float bs0 = bp[wv * 32 + frow];
        float bs1 = bp[wv * 32 + 16 + frow];
        #pragma unroll
        for (int i = 0; i < 4; i++) {
            #pragma unroll
            for (int r = 0; r < 4; r++) {
                int row = i * 16 + fq * 4 + r;
                size_t off = (size_t)(rowA + row) * 128 + wv * 32 + frow;
                float v0 = resin[off] + accP[i][0][r] + bs0;
                float v1 = resin[off + 16] + accP[i][1][r] + bs1;
                resout[off] = v0;
                resout[off + 16] = v1;
                float s = v0 + v1, sq = v0 * v0 + v1 * v1;
                #pragma unroll
                for (int d = 1; d < 16; d <<= 1) { s += __shfl_xor(s, d, 64); sq += __shfl_xor(sq, d, 64); }
                if (frow == 0) { psum[wv * 64 + row] = s; psq[wv * 64 + row] = sq; }
            }
        }
    }
    __syncthreads();

    // ---- phase D: LN(res2) -> lA (stats from LDS; res2 re-read is L1/L2-hot)
    {
        int r = tid >> 2, q = tid & 3;
        float s  = psum[r] + psum[64 + r] + psum[128 + r] + psum[192 + r];
        float sq = psq[r]  + psq[64 + r]  + psq[128 + r]  + psq[192 + r];
        float m = s * (1.0f / 128.0f);
        float inv = rsqrtf(sq * (1.0f / 128.0f) - m * m + 1e-5f);
        const float* rowp = resout + (size_t)(rowA + r) * 128 + q * 32;
        bf16_t* dst = lA + r * LNS + q * 32;
        #pragma unroll
        for (int i = 0; i < 4; i++) {
            float4 a = *(const float4*)(rowp + i * 8);
            float4 b = *(const float4*)(rowp + i * 8 + 4);
            float4 g0 = *(const float4*)(g + q * 32 + i * 8);
            float4 g1 = *(const float4*)(g + q * 32 + i * 8 + 4);
            float4 b0 = *(const float4*)(bta + q * 32 + i * 8);
            float4 b1 = *(const float4*)(bta + q * 32 + i * 8 + 4);
            bf16x8 o;
            o[0] = (bf16_t)((a.x - m) * inv * g0.x + b0.x);
            o[1] = (bf16_t)((a.y - m) * inv * g0.y + b0.y);
            o[2] = (bf16_t)((a.z - m) * inv * g0.z + b0.z);
            o[3] = (bf16_t)((a.w - m) * inv * g0.w + b0.w);
            o[4] = (bf16_t)((b.x - m) * inv * g1.x + b1.x);
            o[5] = (bf16_t)((b.y - m) * inv * g1.y + b1.y);
            o[6] = (bf16_t)((b.z - m) * inv * g1.z + b1.z);
            o[7] = (bf16_t)((b.w - m) * inv * g1.w + b1.w);
            *(bf16x8*)(dst + i * 8) = o;
        }
    }
    __syncthreads();

    // ---- phase E: MLP chunks (R8 structure)
    const bf16_t* pw1 = W1f + lane * 8;
    const bf16_t* pw2 = W2f + lane * 8;
    floatx4 accO[4][2] = {};
    for (int cn = 0; cn < 4; cn++) {
        floatx4 accH[4][2] = {};
        #pragma unroll
        for (int kc = 0; kc < 4; kc++) {
            bf16x8 af[4], bfr[2];
            #pragma unroll
            for (int j = 0; j < 2; j++)
                bfr[j] = *(const bf16x8*)(pw1 + (size_t)((cn * 8 + wv * 2 + j) * 4 + kc) * 512);
            #pragma unroll
            for (int i = 0; i < 4; i++)
                af[i] = *(const bf16x8*)&lA[(i * 16 + frow) * LNS + kc * 32 + fq * 8];
            #pragma unroll
            for (int i = 0; i < 4; i++)
                #pragma unroll
                for (int j = 0; j < 2; j++)
                    accH[i][j] = __builtin_amdgcn_mfma_f32_16x16x32_bf16(af[i], bfr[j], accH[i][j], 0, 0, 0);
        }
        #pragma unroll
        for (int j = 0; j < 2; j++) {
            int col = wv * 32 + j * 16 + frow;
            float bs = b1[cn * 128 + col];
            #pragma unroll
            for (int i = 0; i < 4; i++)
                #pragma unroll
                for (int r = 0; r < 4; r++) {
                    int row = i * 16 + fq * 4 + r;
                    float v = accH[i][j][r] + bs;
                    float u = 1.5957691216057308f * (v + 0.044715f * v * v * v);
                    lH[row * LNS + col] = (bf16_t)(v / (1.0f + __expf(-u)));
                }
        }
        __syncthreads();
        #pragma unroll
        for (int kc = 0; kc < 4; kc++) {
            bf16x8 af[4], bfr[2];
            #pragma unroll
            for (int j = 0; j < 2; j++)
                bfr[j] = *(const bf16x8*)(pw2 + (size_t)((wv * 2 + j) * 16 + cn * 4 + kc) * 512);
            #pragma unroll
            for (int i = 0; i < 4; i++)
                af[i] = *(const bf16x8*)&lH[(i * 16 + frow) * LNS + kc * 32 + fq * 8];
            #pragma unroll
            for (int i = 0; i < 4; i++)
                #pragma unroll
                for (int j = 0; j < 2; j++)
                    accO[i][j] = __builtin_amdgcn_mfma_f32_16x16x32_bf16(af[i], bfr[j], accO[i][j], 0, 0, 0);
        }
        __syncthreads();
    }

    // ---- phase F: final residual write (res2 re-read, L1/L2-hot)
    #pragma unroll
    for (int j = 0; j < 2; j++) {
        int col = wv * 32 + j * 16 + frow;
        float bs = b2[col];
        #pragma unroll
        for (int i = 0; i < 4; i++)
            #pragma unroll
            for (int r = 0; r < 4; r++) {
                int row = rowA + i * 16 + fq * 4 + r;
                size_t off = (size_t)row * 128 + col;
                resout[off] = resout[off] + accO[i][j][r] + bs;
            }
    }
}

// ---------------- reduction GEMM (patch merge): out(M,256) = A(M,512) @ Bf^T
__global__ __launch_bounds__(256, 4) void gemmred(const bf16_t* __restrict__ A,
                                                  const bf16_t* __restrict__ Bf,  // frag (256,512) tilesK=16
                                                  float* __restrict__ outf,
                                                  int M, int N, int K) {
    alignas(16) __shared__ bf16_t lA[2 * 64 * 32];
    const int tid = threadIdx.x;
    const int lane = tid & 63;
    const int wv = tid >> 6;
    const int wm = (wv & 1) * 32;
    const int wn = (wv >> 1) * 64;
    const int frow = lane & 15, fq = lane >> 4;
    const int rowA = blockIdx.y * 64;
    const int rowB = blockIdx.x * 128;
    const int sr = tid >> 2, sc = (tid & 3) * 8;
    const int tilesK = K >> 5;
    const bf16_t* pa = A + (size_t)(rowA + sr) * K + sc;
    const bf16_t* pb = Bf + (size_t)((rowB + wn) >> 4) * tilesK * 512 + lane * 8;
    floatx4 acc[2][4] = {};
    for (int k0 = 0; k0 < K; k0 += 64) {
        __syncthreads();
        gl16(pa + k0,      &lA[tid * 8]);
        gl16(pa + k0 + 32, &lA[2048 + tid * 8]);
        __syncthreads();
        #pragma unroll
        for (int s = 0; s < 2; s++) {
            int kcg = (k0 >> 5) + s;
            bf16x8 af[2], bfr[4];
            #pragma unroll
            for (int j = 0; j < 4; j++)
                bfr[j] = *(const bf16x8*)(pb + (size_t)(j * tilesK + kcg) * 512);
            #pragma unroll
            for (int i = 0; i < 2; i++)
                af[i] = *(const bf16x8*)&lA[s * 2048 + (wm + i * 16 + frow) * 32 + fq * 8];
            #pragma unroll
            for (int i = 0; i < 2; i++)
                #pragma unroll
                for (int j = 0; j < 4; j++)
                    acc[i][j] = __builtin_amdgcn_mfma_f32_16x16x32_bf16(af[i], bfr[j], acc[i][j], 0, 0, 0);
        }
    }
    #pragma unroll
    for (int i = 0; i < 2; i++)
        #pragma unroll
        for (int j = 0; j < 4; j++) {
            int col = rowB + wn + j * 16 + frow;
            #pragma unroll
            for (int r = 0; r < 4; r++) {
                int row = rowA + wm + i * 16 + fq * 4 + r;
                outf[(size_t)row * N + col] = acc[i][j][r];
            }
        }
}

// ---------------- patch-merge gather + LayerNorm over 512 -> bf16
__global__ __launch_bounds__(256) void kmergeln(const float* __restrict__ x, const float* __restrict__ g,
                                                const float* __restrict__ bta, bf16_t* __restrict__ out) {
    int row = blockIdx.x * 4 + (threadIdx.x >> 6);
    int lane = threadIdx.x & 63;
    int b = row / 2304; int rr = row - b * 2304;
    int i2 = rr / 48, j2 = rr - i2 * 48;
    int q = lane >> 4;
    int cc = (lane & 15) * 8;
    int di = q & 1, dj = q >> 1;
    int src = ((b * 96 + i2 * 2 + di) * 96 + (j2 * 2 + dj)) * 128 + cc;
    float4 a0 = *(const float4*)&x[src];
    float4 a1 = *(const float4*)&x[src + 4];
    float s  = a0.x + a0.y + a0.z + a0.w + a1.x + a1.y + a1.z + a1.w;
    float sq = a0.x*a0.x + a0.y*a0.y + a0.z*a0.z + a0.w*a0.w
             + a1.x*a1.x + a1.y*a1.y + a1.z*a1.z + a1.w*a1.w;
    #pragma unroll
    for (int d = 1; d < 64; d <<= 1) { s += __shfl_xor(s, d, 64); sq += __shfl_xor(sq, d, 64); }
    float m = s * (1.0f / 512.0f);
    float var = sq * (1.0f / 512.0f) - m * m;
    float inv = 1.0f / sqrtf(var + 1e-5f);
    int c = q * 128 + cc;
    float4 g0 = *(const float4*)&g[c];
    float4 g1 = *(const float4*)&g[c + 4];
    float4 b0 = *(const float4*)&bta[c];
    float4 b1 = *(const float4*)&bta[c + 4];
    bf16x8 o;
    o[0] = (bf16_t)((a0.x - m) * inv * g0.x + b0.x);
    o[1] = (bf16_t)((a0.y - m) * inv * g0.y + b0.y);
    o[2] = (bf16_t)((a0.z - m) * inv * g0.z + b0.z);
    o[3] = (bf16_t)((a0.w - m) * inv * g0.w + b0.w);
    o[4] = (bf16_t)((a1.x - m) * inv * g1.x + b1.x);
    o[5] = (bf16_t)((a1.y - m) * inv * g1.y + b1.y);
    o[6] = (bf16_t)((a1.z - m) * inv * g1.z + b1.z);
    o[7] = (bf16_t)((a1.w - m) * inv * g1.w + b1.w);
    *(bf16x8*)&out[row * 512 + c] = o;
}

// ---------------- fused window attention: one wave per (window, head)
__global__ __launch_bounds__(64) void kattn(const bf16_t* __restrict__ qkv, bf16_t* __restrict__ out, int shift) {
    alignas(16) __shared__ bf16_t lp[64 * 64];
    alignas(16) __shared__ bf16_t lv[64 * 32];
    int blk = blockIdx.x;
    int win = blk >> 2, h = blk & 3;
    int b = win / 144; int wr = win - b * 144;
    int wi = wr / 12, wj = wr - wi * 12;
    int ri0 = wi * 8, rj0 = wj * 8;
    int lane = threadIdx.x;
    auto trow = [&](int n) {
        int oi = ri0 + (n >> 3) + shift; oi = (oi >= 96) ? oi - 96 : oi;
        int oj = rj0 + (n & 7) + shift;  oj = (oj >= 96) ? oj - 96 : oj;
        return (b * 96 + oi) * 96 + oj;
    };
    {
        size_t base = (size_t)trow(lane) * 384 + 256 + h * 32;
        *(uint4*)&lv[lane * 32]      = *(const uint4*)&qkv[base];
        *(uint4*)&lv[lane * 32 + 8]  = *(const uint4*)&qkv[base + 8];
        *(uint4*)&lv[lane * 32 + 16] = *(const uint4*)&qkv[base + 16];
        *(uint4*)&lv[lane * 32 + 24] = *(const uint4*)&qkv[base + 24];
    }
    int frow = lane & 15, fk = (lane >> 4) * 8;
    bf16x8 qf[4], kf[4];
    #pragma unroll
    for (int t = 0; t < 4; t++) {
        size_t rq = (size_t)trow(t * 16 + frow) * 384;
        qf[t] = *(const bf16x8*)&qkv[rq + h * 32 + fk];
        kf[t] = *(const bf16x8*)&qkv[rq + 128 + h * 32 + fk];
    }
    floatx4 S[4][4] = {};
    #pragma unroll
    for (int mt = 0; mt < 4; mt++)
        #pragma unroll
        for (int nt = 0; nt < 4; nt++)
            S[mt][nt] = __builtin_amdgcn_mfma_f32_16x16x32_bf16(qf[mt], kf[nt], S[mt][nt], 0, 0, 0);
    const float scale = 0.17677669529663687f;
    #pragma unroll
    for (int mt = 0; mt < 4; mt++)
        #pragma unroll
        for (int nt = 0; nt < 4; nt++)
            #pragma unroll
            for (int r = 0; r < 4; r++) S[mt][nt][r] *= scale;
    if (shift > 0) {
        auto grpn = [&](int n) {
            int ri = ri0 + (n >> 3), rj = rj0 + (n & 7);
            int gr = (ri < 88) ? 0 : ((ri < 92) ? 1 : 2);
            int gc = (rj < 88) ? 0 : ((rj < 92) ? 1 : 2);
            return gr * 3 + gc;
        };
        int gk[4];
        #pragma unroll
        for (int nt = 0; nt < 4; nt++) gk[nt] = grpn(nt * 16 + frow);
        #pragma unroll
        for (int mt = 0; mt < 4; mt++)
            #pragma unroll
            for (int r = 0; r < 4; r++) {
                int gq = grpn(mt * 16 + (lane >> 4) * 4 + r);
                #pragma unroll
                for (int nt = 0; nt < 4; nt++)
                    if (gq != gk[nt]) S[mt][nt][r] = -1e30f;
            }
    }
    #pragma unroll
    for (int mt = 0; mt < 4; mt++) {
        #pragma unroll
        for (int r = 0; r < 4; r++) {
            float mx = fmaxf(fmaxf(S[mt][0][r], S[mt][1][r]), fmaxf(S[mt][2][r], S[mt][3][r]));
            #pragma unroll
            for (int d = 1; d < 16; d <<= 1) mx = fmaxf(mx, __shfl_xor(mx, d, 64));
            float sm = 0.0f;
            #pragma unroll
            for (int nt = 0; nt < 4; nt++) {
                float p = __expf(S[mt][nt][r] - mx);
                S[mt][nt][r] = p;
                sm += p;
            }
            #pragma unroll
            for (int d = 1; d < 16; d <<= 1) sm += __shfl_xor(sm, d, 64);
            float inv = 1.0f / sm;
            #pragma unroll
            for (int nt = 0; nt < 4; nt++) S[mt][nt][r] *= inv;
        }
    }
    #pragma unroll
    for (int mt = 0; mt < 4; mt++)
        #pragma unroll
        for (int nt = 0; nt < 4; nt++)
            #pragma unroll
            for (int r = 0; r < 4; r++)
                lp[(mt * 16 + (lane >> 4) * 4 + r) * 64 + nt * 16 + frow] = (bf16_t)S[mt][nt][r];
    __syncthreads();
    floatx4 O[4][2] = {};
    #pragma unroll
    for (int ks = 0; ks < 2; ks++) {
        bf16x8 vbs[2];
        #pragma unroll
        for (int nt = 0; nt < 2; nt++)
            #pragma unroll
            for (int j = 0; j < 8; j++)
                vbs[nt][j] = lv[(ks * 32 + fk + j) * 32 + nt * 16 + frow];
        #pragma unroll
        for (int mt = 0; mt < 4; mt++) {
            bf16x8 pa = *(const bf16x8*)&lp[(mt * 16 + frow) * 64 + ks * 32 + fk];
            #pragma unroll
            for (int nt = 0; nt < 2; nt++)
                O[mt][nt] = __builtin_amdgcn_mfma_f32_16x16x32_bf16(pa, vbs[nt], O[mt][nt], 0, 0, 0);
        }
    }
    #pragma unroll
    for (int mt = 0; mt < 4; mt++) {
        #pragma unroll
        for (int r = 0; r < 4; r++) {
            int qr = mt * 16 + (lane >> 4) * 4 + r;
            size_t orow = (size_t)trow(qr) * 128 + h * 32;
            #pragma unroll
            for (int nt = 0; nt < 2; nt++)
                out[orow + nt * 16 + frow] = (bf16_t)O[mt][nt][r];
        }
    }
}

extern "C" void kernel_launch(void* const* d_in, const int* in_sizes, int n_in,
                              void* d_out, int out_size, void* d_ws, size_t ws_size,
                              hipStream_t stream) {
    const float* x       = (const float*)d_in[0];
    const float* a_ln1g  = (const float*)d_in[1];
    const float* a_ln1b  = (const float*)d_in[2];
    const float* a_qkvw  = (const float*)d_in[3];
    const float* a_qkvb  = (const float*)d_in[4];
    const float* a_projw = (const float*)d_in[5];
    const float* a_projb = (const float*)d_in[6];
    const float* a_ln2g  = (const float*)d_in[7];
    const float* a_ln2b  = (const float*)d_in[8];
    const float* a_fc1w  = (const float*)d_in[9];
    const float* a_fc1b  = (const float*)d_in[10];
    const float* a_fc2w  = (const float*)d_in[11];
    const float* a_fc2b  = (const float*)d_in[12];
    const float* b_ln1g  = (const float*)d_in[13];
    const float* b_ln1b  = (const float*)d_in[14];
    const float* b_qkvw  = (const float*)d_in[15];
    const float* b_qkvb  = (const float*)d_in[16];
    const float* b_projw = (const float*)d_in[17];
    const float* b_projb = (const float*)d_in[18];
    const float* b_ln2g  = (const float*)d_in[19];
    const float* b_ln2b  = (const float*)d_in[20];
    const float* b_fc1w  = (const float*)d_in[21];
    const float* b_fc1b  = (const float*)d_in[22];
    const float* b_fc2w  = (const float*)d_in[23];
    const float* b_fc2b  = (const float*)d_in[24];
    const float* mlng    = (const float*)d_in[25];
    const float* mlnb    = (const float*)d_in[26];
    const float* redw    = (const float*)d_in[27];
    float* out = (float*)d_out;

    // workspace layout
    char* p = (char*)d_ws;
    float*  buf_x   = (float*)p;  p += (size_t)NTOK * 128 * 4;
    bf16_t* buf_qkv = (bf16_t*)p; p += (size_t)NTOK * 384 * 2;
    bf16_t* buf_attn= (bf16_t*)p; p += (size_t)NTOK * 128 * 2;
    bf16_t* buf_mrg = (bf16_t*)p; p += (size_t)18432 * 512 * 2;
    bf16_t* wt      = (bf16_t*)p;
    bf16_t* aqkvF  = wt;
    bf16_t* aprojF = aqkvF  + 384 * 128;
    bf16_t* afc1F  = aprojF + 128 * 128;
    bf16_t* afc2F  = afc1F  + 512 * 128;
    bf16_t* bqkvF  = afc2F  + 128 * 512;
    bf16_t* bprojF = bqkvF  + 384 * 128;
    bf16_t* bfc1F  = bprojF + 128 * 128;
    bf16_t* bfc2F  = bfc1F  + 512 * 128;
    bf16_t* redF   = bfc2F  + 128 * 512;

    TPack tp;
    const float* srcs[9] = {a_qkvw, a_projw, a_fc1w, a_fc2w, b_qkvw, b_projw, b_fc1w, b_fc2w, redw};
    bf16_t* dsts[9] = {aqkvF, aprojF, afc1F, afc2F, bqkvF, bprojF, bfc1F, bfc2F, redF};
    int Ks[9] = {128, 128, 128, 512, 128, 128, 128, 512, 512};
    int Ns[9] = {384, 128, 512, 128, 384, 128, 512, 128, 256};
    for (int i = 0; i < 9; i++) { tp.src[i] = srcs[i]; tp.dst[i] = dsts[i]; tp.K[i] = Ks[i]; tp.N[i] = Ns[i]; }
    kconv_frag<<<dim3(512, 9), dim3(256), 0, stream>>>(tp);

    const dim3 blk256(256);
    const int MG = NTOK / 64;  // 1152

    // ---- block A (W-MSA, shift 0)
    kqkv<<<dim3(3, MG), blk256, 0, stream>>>(x, a_ln1g, a_ln1b, aqkvF, a_qkvb, buf_qkv);
    kattn<<<dim3(1152 * 4), dim3(64), 0, stream>>>(buf_qkv, buf_attn, 0);
    kfused<<<dim3(MG), blk256, 0, stream>>>(buf_attn, aprojF, a_projb, x, buf_x,
                                            a_ln2g, a_ln2b, afc1F, a_fc1b, afc2F, a_fc2b);

    // ---- block B (SW-MSA, shift 4)
    kqkv<<<dim3(3, MG), blk256, 0, stream>>>(buf_x, b_ln1g, b_ln1b, bqkvF, b_qkvb, buf_qkv);
    kattn<<<dim3(1152 * 4), dim3(64), 0, stream>>>(buf_qkv, buf_attn, 4);
    kfused<<<dim3(MG), blk256, 0, stream>>>(buf_attn, bprojF, b_projb, buf_x, buf_x,
                                            b_ln2g, b_ln2b, bfc1F, b_fc1b, bfc2F, b_fc2b);

    // ---- patch merge
    kmergeln<<<dim3(18432 / 4), blk256, 0, stream>>>(buf_x, mlng, mlnb, buf_mrg);
    gemmred<<<dim3(2, 288), blk256, 0, stream>>>(buf_mrg, redF, out, 18432, 256, 512);
}

// Round 10
// 405.777 us; speedup vs baseline: 1.1263x; 1.1263x over previous
//
#include <hip/hip_runtime.h>
#include <hip/hip_bf16.h>

typedef __bf16 bf16_t;
typedef __bf16 bf16x2 __attribute__((ext_vector_type(2)));
typedef __bf16 bf16x8 __attribute__((ext_vector_type(8)));
typedef float floatx4 __attribute__((ext_vector_type(4)));

#define NTOK 73728   // 8*96*96
#define LNS 136      // padded LDS row stride

// async global->LDS, 16B per lane. LDS dest must be wave-uniform base + lane*16.
__device__ __forceinline__ void gl16(const bf16_t* g, bf16_t* l) {
    __builtin_amdgcn_global_load_lds((const __attribute__((address_space(1))) void*)g,
                                     (__attribute__((address_space(3))) void*)l, 16, 0, 0);
}

// LayerNorm a 64x128 fp32 tile -> bf16 LDS row-major [64][LNS].
__device__ __forceinline__ void stage_ln(const float* __restrict__ src, const float* __restrict__ g,
                                         const float* __restrict__ bta, bf16_t* lnA, int tid) {
    int r = tid >> 2, q = tid & 3;
    const float* rowp = src + (size_t)r * 128 + q * 32;
    float4 v[8];
    float s = 0.0f, sq = 0.0f;
    #pragma unroll
    for (int i = 0; i < 8; i++) {
        v[i] = *(const float4*)(rowp + i * 4);
        s += v[i].x + v[i].y + v[i].z + v[i].w;
        sq += v[i].x * v[i].x + v[i].y * v[i].y + v[i].z * v[i].z + v[i].w * v[i].w;
    }
    s += __shfl_xor(s, 1, 64); sq += __shfl_xor(sq, 1, 64);
    s += __shfl_xor(s, 2, 64); sq += __shfl_xor(sq, 2, 64);
    float m = s * (1.0f / 128.0f);
    float inv = rsqrtf(sq * (1.0f / 128.0f) - m * m + 1e-5f);
    bf16_t* dst = lnA + r * LNS + q * 32;
    #pragma unroll
    for (int i = 0; i < 4; i++) {
        float4 a = v[2 * i], b = v[2 * i + 1];
        float4 g0 = *(const float4*)(g + q * 32 + i * 8);
        float4 g1 = *(const float4*)(g + q * 32 + i * 8 + 4);
        float4 b0 = *(const float4*)(bta + q * 32 + i * 8);
        float4 b1 = *(const float4*)(bta + q * 32 + i * 8 + 4);
        bf16x8 o;
        o[0] = (bf16_t)((a.x - m) * inv * g0.x + b0.x);
        o[1] = (bf16_t)((a.y - m) * inv * g0.y + b0.y);
        o[2] = (bf16_t)((a.z - m) * inv * g0.z + b0.z);
        o[3] = (bf16_t)((a.w - m) * inv * g0.w + b0.w);
        o[4] = (bf16_t)((b.x - m) * inv * g1.x + b1.x);
        o[5] = (bf16_t)((b.y - m) * inv * g1.y + b1.y);
        o[6] = (bf16_t)((b.z - m) * inv * g1.z + b1.z);
        o[7] = (bf16_t)((b.w - m) * inv * g1.w + b1.w);
        *(bf16x8*)(dst + i * 8) = o;
    }
}

// ---------------- weight conversion: fp32 row-major (K,N) -> bf16 MFMA-B-fragment order.
struct TPack {
    const float* src[9];
    bf16_t* dst[9];
    int K[9], N[9];
};
__global__ __launch_bounds__(256) void kconv_frag(TPack p) {
    int seg = blockIdx.y;
    int K = p.K[seg], N = p.N[seg];
    int idx = blockIdx.x * 256 + threadIdx.x;
    if (idx >= K * N) return;
    int j = idx & 7;
    int lane = (idx >> 3) & 63;
    int blk = idx >> 9;
    int tilesK = K >> 5;
    int ntile = blk / tilesK, kc = blk - ntile * tilesK;
    int n = ntile * 16 + (lane & 15);
    int k = kc * 32 + (lane >> 4) * 8 + j;
    p.dst[seg][idx] = (bf16_t)p.src[seg][(size_t)k * N + n];
}

// ---------------- fused LN + qkv GEMM: one block per 64-row tile, all 384 cols in 3 chunks.
// x read + LN once (was 3x). Wave = 4m x 2n per chunk.
__global__ __launch_bounds__(256, 4) void kqkv(const float* __restrict__ X,
                                               const float* __restrict__ g, const float* __restrict__ bta,
                                               const bf16_t* __restrict__ Wf,  // frag (384,128) tilesK=4
                                               const float* __restrict__ bias,
                                               bf16_t* __restrict__ out) {
    alignas(16) __shared__ bf16_t lA[64 * LNS];
    const int tid = threadIdx.x;
    const int rowA = blockIdx.x * 64;
    stage_ln(X + (size_t)rowA * 128, g, bta, lA, tid);
    __syncthreads();
    const int lane = tid & 63, wv = tid >> 6;
    const int frow = lane & 15, fq = lane >> 4;
    const bf16_t* pw = Wf + lane * 8;
    for (int cn = 0; cn < 3; cn++) {
        floatx4 acc[4][2] = {};
        #pragma unroll
        for (int kc = 0; kc < 4; kc++) {
            bf16x8 af[4], bfr[2];
            #pragma unroll
            for (int j = 0; j < 2; j++)   // ntile = cn*8 + wv*2 + j
                bfr[j] = *(const bf16x8*)(pw + (size_t)((cn * 8 + wv * 2 + j) * 4 + kc) * 512);
            #pragma unroll
            for (int i = 0; i < 4; i++)
                af[i] = *(const bf16x8*)&lA[(i * 16 + frow) * LNS + kc * 32 + fq * 8];
            #pragma unroll
            for (int i = 0; i < 4; i++)
                #pragma unroll
                for (int j = 0; j < 2; j++)
                    acc[i][j] = __builtin_amdgcn_mfma_f32_16x16x32_bf16(af[i], bfr[j], acc[i][j], 0, 0, 0);
        }
        #pragma unroll
        for (int j = 0; j < 2; j++) {
            int col = cn * 128 + wv * 32 + j * 16 + frow;
            float bs = bias[col];
            #pragma unroll
            for (int i = 0; i < 4; i++)
                #pragma unroll
                for (int r = 0; r < 4; r++) {
                    int row = rowA + i * 16 + fq * 4 + r;
                    out[(size_t)row * 384 + col] = (bf16_t)(acc[i][j][r] + bs);
                }
        }
    }
}

// ---------------- fused proj + LN2 + MLP, res2 register-resident (never hits HBM):
//   res2 = resin + attn@Wp^T + bp   (registers, C-layout)
//   resout = res2 + gelu(LN(res2)@W1^T+b1)@W2^T + b2   (single store, no re-reads)
__global__ __launch_bounds__(256, 3) void kfused(const bf16_t* __restrict__ attn,
                                                 const bf16_t* __restrict__ Wpf,  // proj frag (128,128) tilesK=4
                                                 const float* __restrict__ bp,
                                                 const float* __restrict__ resin,
                                                 float* __restrict__ resout,
                                                 const float* __restrict__ g, const float* __restrict__ bta,
                                                 const bf16_t* __restrict__ W1f,  // frag (512,128) tilesK=4
                                                 const float* __restrict__ b1,
                                                 const bf16_t* __restrict__ W2f,  // frag (128,512) tilesK=16
                                                 const float* __restrict__ b2) {
    alignas(16) __shared__ bf16_t lA[64 * LNS];   // attn panels (16KB), then ln(res2)
    alignas(16) __shared__ bf16_t lH[64 * LNS];   // h chunk
    __shared__ float psum[4 * 64], psq[4 * 64];
    const int tid = threadIdx.x;
    const int rowA = blockIdx.x * 64;
    const int lane = tid & 63, wv = tid >> 6;
    const int frow = lane & 15, fq = lane >> 4;

    // ---- phase A: stage attn tile into 4 k-panels (alias lA)
    {
        const int sr = tid >> 2, sc = (tid & 3) * 8;
        const bf16_t* pa = attn + (size_t)(rowA + sr) * 128 + sc;
        gl16(pa,      &lA[tid * 8]);
        gl16(pa + 32, &lA[2048 + tid * 8]);
        gl16(pa + 64, &lA[4096 + tid * 8]);
        gl16(pa + 96, &lA[6144 + tid * 8]);
    }
    __syncthreads();

    // ---- phase B: proj gemm -> accP
    floatx4 accP[4][2] = {};
    {
        const bf16_t* pw = Wpf + (size_t)(wv * 2) * 4 * 512 + lane * 8;
        #pragma unroll
        for (int kc = 0; kc < 4; kc++) {
            bf16x8 af[4], bfr[2];
            #pragma unroll
            for (int j = 0; j < 2; j++)
                bfr[j] = *(const bf16x8*)(pw + (size_t)(j * 4 + kc) * 512);
            #pragma unroll
            for (int i = 0; i < 4; i++)
                af[i] = *(const bf16x8*)&lA[kc * 2048 + (i * 16 + frow) * 32 + fq * 8];
            #pragma unroll
            for (int i = 0; i < 4; i++)
                #pragma unroll
                for (int j = 0; j < 2; j++)
                    accP[i][j] = __builtin_amdgcn_mfma_f32_16x16x32_bf16(af[i], bfr[j], accP[i][j], 0, 0, 0);
        }
    }

    // ---- phase C: res2 = resin + accP + bp (kept in accP registers); per-row LN partials
    {
        float bs0 = bp[wv * 32 + frow];
        float bs1 = bp[wv * 32 + 16 + frow];
        #pragma unroll
        for (int i = 0; i < 4; i++) {
            #pragma unroll
            for (int r = 0; r < 4; r++) {
                int row = i * 16 + fq * 4 + r;
                size_t off = (size_t)(rowA + row) * 128 + wv * 32 + frow;
                float v0 = resin[off] + accP[i][0][r] + bs0;
                float v1 = resin[off + 16] + accP[i][1][r] + bs1;
                accP[i][0][r] = v0;
                accP[i][1][r] = v1;
                float s = v0 + v1, sq = v0 * v0 + v1 * v1;
                #pragma unroll
                for (int d = 1; d < 16; d <<= 1) { s += __shfl_xor(s, d, 64); sq += __shfl_xor(sq, d, 64); }
                if (frow == 0) { psum[wv * 64 + row] = s; psq[wv * 64 + row] = sq; }
            }
        }
    }
    __syncthreads();   // psum ready; all waves done reading lA panels

    // ---- phase D: LN(res2) from registers -> lA (no global re-read)
    {
        float g0 = g[wv * 32 + frow],      b0 = bta[wv * 32 + frow];
        float g1 = g[wv * 32 + 16 + frow], b1v = bta[wv * 32 + 16 + frow];
        #pragma unroll
        for (int i = 0; i < 4; i++) {
            #pragma unroll
            for (int r = 0; r < 4; r++) {
                int row = i * 16 + fq * 4 + r;
                float s  = psum[row] + psum[64 + row] + psum[128 + row] + psum[192 + row];
                float sq = psq[row]  + psq[64 + row]  + psq[128 + row]  + psq[192 + row];
                float m = s * (1.0f / 128.0f);
                float inv = rsqrtf(sq * (1.0f / 128.0f) - m * m + 1e-5f);
                lA[row * LNS + wv * 32 + frow]      = (bf16_t)((accP[i][0][r] - m) * inv * g0 + b0);
                lA[row * LNS + wv * 32 + 16 + frow] = (bf16_t)((accP[i][1][r] - m) * inv * g1 + b1v);
            }
        }
    }
    __syncthreads();

    // ---- phase E: MLP chunks
    const bf16_t* pw1 = W1f + lane * 8;
    const bf16_t* pw2 = W2f + lane * 8;
    floatx4 accO[4][2] = {};
    for (int cn = 0; cn < 4; cn++) {
        floatx4 accH[4][2] = {};
        #pragma unroll
        for (int kc = 0; kc < 4; kc++) {
            bf16x8 af[4], bfr[2];
            #pragma unroll
            for (int j = 0; j < 2; j++)
                bfr[j] = *(const bf16x8*)(pw1 + (size_t)((cn * 8 + wv * 2 + j) * 4 + kc) * 512);
            #pragma unroll
            for (int i = 0; i < 4; i++)
                af[i] = *(const bf16x8*)&lA[(i * 16 + frow) * LNS + kc * 32 + fq * 8];
            #pragma unroll
            for (int i = 0; i < 4; i++)
                #pragma unroll
                for (int j = 0; j < 2; j++)
                    accH[i][j] = __builtin_amdgcn_mfma_f32_16x16x32_bf16(af[i], bfr[j], accH[i][j], 0, 0, 0);
        }
        #pragma unroll
        for (int j = 0; j < 2; j++) {
            int col = wv * 32 + j * 16 + frow;
            float bs = b1[cn * 128 + col];
            #pragma unroll
            for (int i = 0; i < 4; i++)
                #pragma unroll
                for (int r = 0; r < 4; r++) {
                    int row = i * 16 + fq * 4 + r;
                    float v = accH[i][j][r] + bs;
                    float u = 1.5957691216057308f * (v + 0.044715f * v * v * v);
                    lH[row * LNS + col] = (bf16_t)(v / (1.0f + __expf(-u)));
                }
        }
        __syncthreads();
        #pragma unroll
        for (int kc = 0; kc < 4; kc++) {
            bf16x8 af[4], bfr[2];
            #pragma unroll
            for (int j = 0; j < 2; j++)
                bfr[j] = *(const bf16x8*)(pw2 + (size_t)((wv * 2 + j) * 16 + cn * 4 + kc) * 512);
            #pragma unroll
            for (int i = 0; i < 4; i++)
                af[i] = *(const bf16x8*)&lH[(i * 16 + frow) * LNS + kc * 32 + fq * 8];
            #pragma unroll
            for (int i = 0; i < 4; i++)
                #pragma unroll
                for (int j = 0; j < 2; j++)
                    accO[i][j] = __builtin_amdgcn_mfma_f32_16x16x32_bf16(af[i], bfr[j], accO[i][j], 0, 0, 0);
        }
        __syncthreads();
    }

    // ---- phase F: single final store (res2 from registers, no reads)
    #pragma unroll
    for (int j = 0; j < 2; j++) {
        int col = wv * 32 + j * 16 + frow;
        float bs = b2[col];
        #pragma unroll
        for (int i = 0; i < 4; i++)
            #pragma unroll
            for (int r = 0; r < 4; r++) {
                int row = rowA + i * 16 + fq * 4 + r;
                resout[(size_t)row * 128 + col] = accP[i][j][r] + accO[i][j][r] + bs;
            }
    }
}

// ---------------- reduction GEMM (patch merge): out(M,256) = A(M,512) @ Bf^T
__global__ __launch_bounds__(256, 4) void gemmred(const bf16_t* __restrict__ A,
                                                  const bf16_t* __restrict__ Bf,  // frag (256,512) tilesK=16
                                                  float* __restrict__ outf,
                                                  int M, int N, int K) {
    alignas(16) __shared__ bf16_t lA[2 * 64 * 32];
    const int tid = threadIdx.x;
    const int lane = tid & 63;
    const int wv = tid >> 6;
    const int wm = (wv & 1) * 32;
    const int wn = (wv >> 1) * 64;
    const int frow = lane & 15, fq = lane >> 4;
    const int rowA = blockIdx.y * 64;
    const int rowB = blockIdx.x * 128;
    const int sr = tid >> 2, sc = (tid & 3) * 8;
    const int tilesK = K >> 5;
    const bf16_t* pa = A + (size_t)(rowA + sr) * K + sc;
    const bf16_t* pb = Bf + (size_t)((rowB + wn) >> 4) * tilesK * 512 + lane * 8;
    floatx4 acc[2][4] = {};
    for (int k0 = 0; k0 < K; k0 += 64) {
        __syncthreads();
        gl16(pa + k0,      &lA[tid * 8]);
        gl16(pa + k0 + 32, &lA[2048 + tid * 8]);
        __syncthreads();
        #pragma unroll
        for (int s = 0; s < 2; s++) {
            int kcg = (k0 >> 5) + s;
            bf16x8 af[2], bfr[4];
            #pragma unroll
            for (int j = 0; j < 4; j++)
                bfr[j] = *(const bf16x8*)(pb + (size_t)(j * tilesK + kcg) * 512);
            #pragma unroll
            for (int i = 0; i < 2; i++)
                af[i] = *(const bf16x8*)&lA[s * 2048 + (wm + i * 16 + frow) * 32 + fq * 8];
            #pragma unroll
            for (int i = 0; i < 2; i++)
                #pragma unroll
                for (int j = 0; j < 4; j++)
                    acc[i][j] = __builtin_amdgcn_mfma_f32_16x16x32_bf16(af[i], bfr[j], acc[i][j], 0, 0, 0);
        }
    }
    #pragma unroll
    for (int i = 0; i < 2; i++)
        #pragma unroll
        for (int j = 0; j < 4; j++) {
            int col = rowB + wn + j * 16 + frow;
            #pragma unroll
            for (int r = 0; r < 4; r++) {
                int row = rowA + wm + i * 16 + fq * 4 + r;
                outf[(size_t)row * N + col] = acc[i][j][r];
            }
        }
}

// ---------------- patch-merge gather + LayerNorm over 512 -> bf16
__global__ __launch_bounds__(256) void kmergeln(const float* __restrict__ x, const float* __restrict__ g,
                                                const float* __restrict__ bta, bf16_t* __restrict__ out) {
    int row = blockIdx.x * 4 + (threadIdx.x >> 6);
    int lane = threadIdx.x & 63;
    int b = row / 2304; int rr = row - b * 2304;
    int i2 = rr / 48, j2 = rr - i2 * 48;
    int q = lane >> 4;
    int cc = (lane & 15) * 8;
    int di = q & 1, dj = q >> 1;
    int src = ((b * 96 + i2 * 2 + di) * 96 + (j2 * 2 + dj)) * 128 + cc;
    float4 a0 = *(const float4*)&x[src];
    float4 a1 = *(const float4*)&x[src + 4];
    float s  = a0.x + a0.y + a0.z + a0.w + a1.x + a1.y + a1.z + a1.w;
    float sq = a0.x*a0.x + a0.y*a0.y + a0.z*a0.z + a0.w*a0.w
             + a1.x*a1.x + a1.y*a1.y + a1.z*a1.z + a1.w*a1.w;
    #pragma unroll
    for (int d = 1; d < 64; d <<= 1) { s += __shfl_xor(s, d, 64); sq += __shfl_xor(sq, d, 64); }
    float m = s * (1.0f / 512.0f);
    float var = sq * (1.0f / 512.0f) - m * m;
    float inv = 1.0f / sqrtf(var + 1e-5f);
    int c = q * 128 + cc;
    float4 g0 = *(const float4*)&g[c];
    float4 g1 = *(const float4*)&g[c + 4];
    float4 b0 = *(const float4*)&bta[c];
    float4 b1 = *(const float4*)&bta[c + 4];
    bf16x8 o;
    o[0] = (bf16_t)((a0.x - m) * inv * g0.x + b0.x);
    o[1] = (bf16_t)((a0.y - m) * inv * g0.y + b0.y);
    o[2] = (bf16_t)((a0.z - m) * inv * g0.z + b0.z);
    o[3] = (bf16_t)((a0.w - m) * inv * g0.w + b0.w);
    o[4] = (bf16_t)((a1.x - m) * inv * g1.x + b1.x);
    o[5] = (bf16_t)((a1.y - m) * inv * g1.y + b1.y);
    o[6] = (bf16_t)((a1.z - m) * inv * g1.z + b1.z);
    o[7] = (bf16_t)((a1.w - m) * inv * g1.w + b1.w);
    *(bf16x8*)&out[row * 512 + c] = o;
}

// ---------------- fused window attention: one wave per (window, head)
__global__ __launch_bounds__(64) void kattn(const bf16_t* __restrict__ qkv, bf16_t* __restrict__ out, int shift) {
    alignas(16) __shared__ bf16_t lp[64 * 64];
    alignas(16) __shared__ bf16_t lv[64 * 32];
    int blk = blockIdx.x;
    int win = blk >> 2, h = blk & 3;
    int b = win / 144; int wr = win - b * 144;
    int wi = wr / 12, wj = wr - wi * 12;
    int ri0 = wi * 8, rj0 = wj * 8;
    int lane = threadIdx.x;
    auto trow = [&](int n) {
        int oi = ri0 + (n >> 3) + shift; oi = (oi >= 96) ? oi - 96 : oi;
        int oj = rj0 + (n & 7) + shift;  oj = (oj >= 96) ? oj - 96 : oj;
        return (b * 96 + oi) * 96 + oj;
    };
    {
        size_t base = (size_t)trow(lane) * 384 + 256 + h * 32;
        *(uint4*)&lv[lane * 32]      = *(const uint4*)&qkv[base];
        *(uint4*)&lv[lane * 32 + 8]  = *(const uint4*)&qkv[base + 8];
        *(uint4*)&lv[lane * 32 + 16] = *(const uint4*)&qkv[base + 16];
        *(uint4*)&lv[lane * 32 + 24] = *(const uint4*)&qkv[base + 24];
    }
    int frow = lane & 15, fk = (lane >> 4) * 8;
    bf16x8 qf[4], kf[4];
    #pragma unroll
    for (int t = 0; t < 4; t++) {
        size_t rq = (size_t)trow(t * 16 + frow) * 384;
        qf[t] = *(const bf16x8*)&qkv[rq + h * 32 + fk];
        kf[t] = *(const bf16x8*)&qkv[rq + 128 + h * 32 + fk];
    }
    floatx4 S[4][4] = {};
    #pragma unroll
    for (int mt = 0; mt < 4; mt++)
        #pragma unroll
        for (int nt = 0; nt < 4; nt++)
            S[mt][nt] = __builtin_amdgcn_mfma_f32_16x16x32_bf16(qf[mt], kf[nt], S[mt][nt], 0, 0, 0);
    const float scale = 0.17677669529663687f;
    #pragma unroll
    for (int mt = 0; mt < 4; mt++)
        #pragma unroll
        for (int nt = 0; nt < 4; nt++)
            #pragma unroll
            for (int r = 0; r < 4; r++) S[mt][nt][r] *= scale;
    if (shift > 0) {
        auto grpn = [&](int n) {
            int ri = ri0 + (n >> 3), rj = rj0 + (n & 7);
            int gr = (ri < 88) ? 0 : ((ri < 92) ? 1 : 2);
            int gc = (rj < 88) ? 0 : ((rj < 92) ? 1 : 2);
            return gr * 3 + gc;
        };
        int gk[4];
        #pragma unroll
        for (int nt = 0; nt < 4; nt++) gk[nt] = grpn(nt * 16 + frow);
        #pragma unroll
        for (int mt = 0; mt < 4; mt++)
            #pragma unroll
            for (int r = 0; r < 4; r++) {
                int gq = grpn(mt * 16 + (lane >> 4) * 4 + r);
                #pragma unroll
                for (int nt = 0; nt < 4; nt++)
                    if (gq != gk[nt]) S[mt][nt][r] = -1e30f;
            }
    }
    #pragma unroll
    for (int mt = 0; mt < 4; mt++) {
        #pragma unroll
        for (int r = 0; r < 4; r++) {
            float mx = fmaxf(fmaxf(S[mt][0][r], S[mt][1][r]), fmaxf(S[mt][2][r], S[mt][3][r]));
            #pragma unroll
            for (int d = 1; d < 16; d <<= 1) mx = fmaxf(mx, __shfl_xor(mx, d, 64));
            float sm = 0.0f;
            #pragma unroll
            for (int nt = 0; nt < 4; nt++) {
                float p = __expf(S[mt][nt][r] - mx);
                S[mt][nt][r] = p;
                sm += p;
            }
            #pragma unroll
            for (int d = 1; d < 16; d <<= 1) sm += __shfl_xor(sm, d, 64);
            float inv = 1.0f / sm;
            #pragma unroll
            for (int nt = 0; nt < 4; nt++) S[mt][nt][r] *= inv;
        }
    }
    #pragma unroll
    for (int mt = 0; mt < 4; mt++)
        #pragma unroll
        for (int nt = 0; nt < 4; nt++)
            #pragma unroll
            for (int r = 0; r < 4; r++)
                lp[(mt * 16 + (lane >> 4) * 4 + r) * 64 + nt * 16 + frow] = (bf16_t)S[mt][nt][r];
    __syncthreads();
    floatx4 O[4][2] = {};
    #pragma unroll
    for (int ks = 0; ks < 2; ks++) {
        bf16x8 vbs[2];
        #pragma unroll
        for (int nt = 0; nt < 2; nt++)
            #pragma unroll
            for (int j = 0; j < 8; j++)
                vbs[nt][j] = lv[(ks * 32 + fk + j) * 32 + nt * 16 + frow];
        #pragma unroll
        for (int mt = 0; mt < 4; mt++) {
            bf16x8 pa = *(const bf16x8*)&lp[(mt * 16 + frow) * 64 + ks * 32 + fk];
            #pragma unroll
            for (int nt = 0; nt < 2; nt++)
                O[mt][nt] = __builtin_amdgcn_mfma_f32_16x16x32_bf16(pa, vbs[nt], O[mt][nt], 0, 0, 0);
        }
    }
    #pragma unroll
    for (int mt = 0; mt < 4; mt++) {
        #pragma unroll
        for (int r = 0; r < 4; r++) {
            int qr = mt * 16 + (lane >> 4) * 4 + r;
            size_t orow = (size_t)trow(qr) * 128 + h * 32;
            #pragma unroll
            for (int nt = 0; nt < 2; nt++)
                out[orow + nt * 16 + frow] = (bf16_t)O[mt][nt][r];
        }
    }
}

extern "C" void kernel_launch(void* const* d_in, const int* in_sizes, int n_in,
                              void* d_out, int out_size, void* d_ws, size_t ws_size,
                              hipStream_t stream) {
    const float* x       = (const float*)d_in[0];
    const float* a_ln1g  = (const float*)d_in[1];
    const float* a_ln1b  = (const float*)d_in[2];
    const float* a_qkvw  = (const float*)d_in[3];
    const float* a_qkvb  = (const float*)d_in[4];
    const float* a_projw = (const float*)d_in[5];
    const float* a_projb = (const float*)d_in[6];
    const float* a_ln2g  = (const float*)d_in[7];
    const float* a_ln2b  = (const float*)d_in[8];
    const float* a_fc1w  = (const float*)d_in[9];
    const float* a_fc1b  = (const float*)d_in[10];
    const float* a_fc2w  = (const float*)d_in[11];
    const float* a_fc2b  = (const float*)d_in[12];
    const float* b_ln1g  = (const float*)d_in[13];
    const float* b_ln1b  = (const float*)d_in[14];
    const float* b_qkvw  = (const float*)d_in[15];
    const float* b_qkvb  = (const float*)d_in[16];
    const float* b_projw = (const float*)d_in[17];
    const float* b_projb = (const float*)d_in[18];
    const float* b_ln2g  = (const float*)d_in[19];
    const float* b_ln2b  = (const float*)d_in[20];
    const float* b_fc1w  = (const float*)d_in[21];
    const float* b_fc1b  = (const float*)d_in[22];
    const float* b_fc2w  = (const float*)d_in[23];
    const float* b_fc2b  = (const float*)d_in[24];
    const float* mlng    = (const float*)d_in[25];
    const float* mlnb    = (const float*)d_in[26];
    const float* redw    = (const float*)d_in[27];
    float* out = (float*)d_out;

    // workspace layout
    char* p = (char*)d_ws;
    float*  buf_x   = (float*)p;  p += (size_t)NTOK * 128 * 4;
    bf16_t* buf_qkv = (bf16_t*)p; p += (size_t)NTOK * 384 * 2;
    bf16_t* buf_attn= (bf16_t*)p; p += (size_t)NTOK * 128 * 2;
    bf16_t* buf_mrg = (bf16_t*)p; p += (size_t)18432 * 512 * 2;
    bf16_t* wt      = (bf16_t*)p;
    bf16_t* aqkvF  = wt;
    bf16_t* aprojF = aqkvF  + 384 * 128;
    bf16_t* afc1F  = aprojF + 128 * 128;
    bf16_t* afc2F  = afc1F  + 512 * 128;
    bf16_t* bqkvF  = afc2F  + 128 * 512;
    bf16_t* bprojF = bqkvF  + 384 * 128;
    bf16_t* bfc1F  = bprojF + 128 * 128;
    bf16_t* bfc2F  = bfc1F  + 512 * 128;
    bf16_t* redF   = bfc2F  + 128 * 512;

    TPack tp;
    const float* srcs[9] = {a_qkvw, a_projw, a_fc1w, a_fc2w, b_qkvw, b_projw, b_fc1w, b_fc2w, redw};
    bf16_t* dsts[9] = {aqkvF, aprojF, afc1F, afc2F, bqkvF, bprojF, bfc1F, bfc2F, redF};
    int Ks[9] = {128, 128, 128, 512, 128, 128, 128, 512, 512};
    int Ns[9] = {384, 128, 512, 128, 384, 128, 512, 128, 256};
    for (int i = 0; i < 9; i++) { tp.src[i] = srcs[i]; tp.dst[i] = dsts[i]; tp.K[i] = Ks[i]; tp.N[i] = Ns[i]; }
    kconv_frag<<<dim3(512, 9), dim3(256), 0, stream>>>(tp);

    const dim3 blk256(256);
    const int MG = NTOK / 64;  // 1152

    // ---- block A (W-MSA, shift 0)
    kqkv<<<dim3(MG), blk256, 0, stream>>>(x, a_ln1g, a_ln1b, aqkvF, a_qkvb, buf_qkv);
    kattn<<<dim3(1152 * 4), dim3(64), 0, stream>>>(buf_qkv, buf_attn, 0);
    kfused<<<dim3(MG), blk256, 0, stream>>>(buf_attn, aprojF, a_projb, x, buf_x,
                                            a_ln2g, a_ln2b, afc1F, a_fc1b, afc2F, a_fc2b);

    // ---- block B (SW-MSA, shift 4)
    kqkv<<<dim3(MG), blk256, 0, stream>>>(buf_x, b_ln1g, b_ln1b, bqkvF, b_qkvb, buf_qkv);
    kattn<<<dim3(1152 * 4), dim3(64), 0, stream>>>(buf_qkv, buf_attn, 4);
    kfused<<<dim3(MG), blk256, 0, stream>>>(buf_attn, bprojF, b_projb, buf_x, buf_x,
                                            b_ln2g, b_ln2b, bfc1F, b_fc1b, bfc2F, b_fc2b);

    // ---- patch merge
    kmergeln<<<dim3(18432 / 4), blk256, 0, stream>>>(buf_x, mlng, mlnb, buf_mrg);
    gemmred<<<dim3(2, 288), blk256, 0, stream>>>(buf_mrg, redF, out, 18432, 256, 512);
}